// Round 10
// baseline (224.977 us; speedup 1.0000x reference)
//
#include <hip/hip_runtime.h>
#include <math.h>

// ---------------------------------------------------------------------------
// KAN-Conv CIFAR net on gfx950, round 10.
// Round-9 engine (LDS act planes, wave-uniform channel -> scalar-pipe weight
// loads, full-O act reuse, 3 barriers, parallel reduce+shfl-maxpool) with:
//  - tiles resized for residency: L1 20KB/NT384 (5 blk/CU), L2 29KB/NT256
//    (5 blk/CU), L3 51KB unpadded (3 blk/CU; 2-way LDS aliasing is free)
//  - f-major fused weight layout [F][O][8]: per-tap OB weight records are
//    contiguous (512B) -> scalar-cache friendly s_load_dwordx8 runs.
// ---------------------------------------------------------------------------

#define BATCH 256

__device__ __forceinline__ void bspline_basis(float x, float bs[6]) {
    const float h = 2.0f / 3.0f;
    float g[10];
#pragma unroll
    for (int i = 0; i < 10; ++i) g[i] = (float)(i - 3) * h - 1.0f;
    float b[9];
#pragma unroll
    for (int i = 0; i < 9; ++i) b[i] = (x >= g[i] && x < g[i + 1]) ? 1.0f : 0.0f;
#pragma unroll
    for (int j = 1; j <= 3; ++j) {
        const float inv_d = 1.0f / ((float)j * h);
#pragma unroll
        for (int i = 0; i + j < 9; ++i) {
            float left  = (x - g[i]) * inv_d;
            float right = (g[i + j + 1] - x) * inv_d;
            b[i] = left * b[i] + right * b[i + 1];
        }
    }
#pragma unroll
    for (int i = 0; i < 6; ++i) bs[i] = b[i];
}

// Fuse {base_w, spline_w*scaler} into f-major 8-float records:
// dst[(f*O + o)*8 + k]  (k: bw, sw0..sw5*sc, 0)
__global__ __launch_bounds__(256) void prep_weights(
        const float* __restrict__ bw1, const float* __restrict__ sw1, const float* __restrict__ sc1,
        const float* __restrict__ bw2, const float* __restrict__ sw2, const float* __restrict__ sc2,
        const float* __restrict__ bw3, const float* __restrict__ sw3, const float* __restrict__ sc3,
        float* __restrict__ w1, float* __restrict__ w2, float* __restrict__ w3) {
    int i = blockIdx.x * blockDim.x + threadIdx.x;
    const float *bw, *sw, *sc;
    float* dst;
    int j, O, F;
    if (i < 216)       { bw = bw1; sw = sw1; sc = sc1; dst = w1; j = i;        O = 8;  F = 27; }
    else if (i < 1368) { bw = bw2; sw = sw2; sc = sc2; dst = w2; j = i - 216;  O = 16; F = 72; }
    else if (i < 5976) { bw = bw3; sw = sw3; sc = sc3; dst = w3; j = i - 1368; O = 32; F = 144; }
    else return;
    const int o = j / F, f = j % F;
    float s = sc[j];
    float4* d4 = (float4*)(dst + (size_t)(f * O + o) * 8);
    d4[0] = make_float4(bw[j], sw[j * 6 + 0] * s, sw[j * 6 + 1] * s, sw[j * 6 + 2] * s);
    d4[1] = make_float4(sw[j * 6 + 3] * s, sw[j * 6 + 4] * s, sw[j * 6 + 5] * s, 0.0f);
}

// One fused KAN conv3x3(pad1)+maxpool2 layer.
// Block = (image b, row-strip v of CR conv rows, o-split os of OB channels).
// Taps: tid = fh*POS + pos; fh wave-uniform; weights scalar-loaded (f-major).
template <int C, int O, int OB, int H, int W, int CR, int CPF, int NT, int OS, int PAD>
__global__ __launch_bounds__(NT, 4) void kan_conv(
        const float* __restrict__ src,    // [B, C, H, W]
        const float* __restrict__ wrec,   // [C*9, O, 8] fused, f-major
        float* __restrict__ dst) {        // [B, O, H/2, W/2]
    constexpr int PH = H / 2, PW = W / 2;
    constexpr int VS  = H / CR;
    constexpr int POS = CR * W;            // conv positions per block
    constexpr int FS  = C / CPF;           // fh groups
    constexpr int NA  = FS * POS;          // active tap threads
    constexpr int F   = C * 9;
    constexpr int R   = CR + 2;            // staged rows incl. halo
    constexpr int TC  = W + 2;             // staged cols incl. halo
    constexpr int CP  = TC / 2;            // cols per parity plane
    constexpr int RST = 2 * CP + PAD;      // row stride (f4)
    constexpr int CST = R * RST;           // channel stride (f4)
    constexpr int PLANE = C * CST;
    constexpr int ACT4  = 2 * PLANE;
    static_assert(POS % 64 == 0, "fh wave-uniform");
    static_assert(NA <= NT, "tap threads fit");
    static_assert(NT % 64 == 0, "wave multiple");
    static_assert(NA * OB <= ACT4 * 4, "scratch fits in act region");
    static_assert((OB * POS) % 64 == 0, "pool groups wave-aligned");

    __shared__ float4 s_act4[ACT4];
    float* scr = (float*)s_act4;

    const int tid = threadIdx.x;
    const int bx  = blockIdx.x;
    const int b   = bx / (VS * OS);
    const int rem = bx % (VS * OS);
    const int v   = rem / OS;
    const int os  = rem % OS;
    const int o0  = os * OB;
    const int r0  = v * CR - 1;            // global row of staged row 0

    // ---- Phase 1: stage zero-padded src -> [silu | b0..b5] act planes
    const float* sb = src + (size_t)b * C * H * W;
    for (int i = tid; i < C * R * TC; i += NT) {
        const int cc  = i / (R * TC);
        const int rr  = (i / TC) % R;
        const int col = i % TC;
        const int gr = r0 + rr, gc = col - 1;
        float val = 0.f;
        if ((unsigned)gr < (unsigned)H && (unsigned)gc < (unsigned)W)
            val = sb[(cc * H + gr) * W + gc];
        const float silu = val / (1.f + __expf(-val));
        float bs[6];
        bspline_basis(val, bs);
        const int idx = cc * CST + rr * RST + (col & 1) * CP + (col >> 1);
        s_act4[idx]         = make_float4(silu, bs[0], bs[1], bs[2]);
        s_act4[PLANE + idx] = make_float4(bs[3], bs[4], bs[5], 0.f);
    }
    __syncthreads();

    // ---- Phase 2: taps. One conv position per thread, OB outputs, CPF chans.
    const int pos = tid % POS;
    const int fh  = __builtin_amdgcn_readfirstlane(tid / POS);
    const int y = pos / W, xx = pos % W;

    float acc[OB];
#pragma unroll
    for (int o = 0; o < OB; ++o) acc[o] = 0.f;

    if (tid < NA) {
#pragma unroll 1
        for (int cp = 0; cp < CPF; ++cp) {
            const int c = fh * CPF + cp;
            const float4* plo = s_act4 + c * CST;
            const float4* phi = plo + PLANE;
#pragma unroll 1
            for (int ky = 0; ky < 3; ++ky) {
                const int rr = y + ky;
#pragma unroll
                for (int kx = 0; kx < 3; ++kx) {
                    const int col = xx + kx;
                    const int idx = rr * RST + (col & 1) * CP + (col >> 1);
                    const float4 lo = plo[idx];
                    const float4 hi = phi[idx];
                    // f-major: OB records contiguous at this tap
                    const float* wt = wrec +
                        ((size_t)(c * 9 + ky * 3 + kx) * O + o0) * 8;
#pragma unroll
                    for (int o = 0; o < OB; ++o) {
                        const float* w = wt + (size_t)o * 8;   // scalar loads
                        acc[o] += lo.x * w[0] + lo.y * w[1] + lo.z * w[2] +
                                  lo.w * w[3] + hi.x * w[4] + hi.y * w[5] +
                                  hi.z * w[6];
                    }
                }
            }
        }
    }
    __syncthreads();                       // act reads done; reuse as scratch

    // ---- Phase 3: write partials, o-major f32
    if (tid < NA) {
#pragma unroll
        for (int o = 0; o < OB; ++o)
            scr[(o * FS + fh) * POS + pos] = acc[o];
    }
    __syncthreads();

    // ---- Phase 4: parallel reduce over fh + 2x2 shfl maxpool + global store
    for (int a = tid; a < OB * POS; a += NT) {
        const int oq = a / POS;
        const int p2 = a % POS;
        float s = 0.f;
#pragma unroll
        for (int f = 0; f < FS; ++f) s += scr[(oq * FS + f) * POS + p2];
        s = fmaxf(s, __shfl_xor(s, 1));    // pool over x
        s = fmaxf(s, __shfl_xor(s, W));    // pool over y
        const int yy = p2 / W, xq = p2 % W;
        if (!(xq & 1) && !(yy & 1)) {
            const int ph = (v * CR + yy) >> 1, pw = xq >> 1;
            dst[(((size_t)b * O + o0 + oq) * PH + ph) * PW + pw] = s;
        }
    }
}

// out[n,o] = dot(h[n,:512], w[o,:512]) + bias[o]
__global__ __launch_bounds__(256) void linear_kernel(const float* __restrict__ h,
                                                     const float* __restrict__ w,
                                                     const float* __restrict__ bias,
                                                     float* __restrict__ out) {
    int idx = blockIdx.x * blockDim.x + threadIdx.x;
    if (idx >= BATCH * 100) return;
    int o = idx % 100;
    int n = idx / 100;
    const float4* hp = (const float4*)(h + (size_t)n * 512);
    const float4* wp = (const float4*)(w + (size_t)o * 512);
    float acc = 0.f;
#pragma unroll 4
    for (int i = 0; i < 128; ++i) {
        float4 a = hp[i];
        float4 b = wp[i];
        acc += a.x * b.x + a.y * b.y + a.z * b.z + a.w * b.w;
    }
    out[idx] = acc + bias[o];
}

extern "C" void kernel_launch(void* const* d_in, const int* in_sizes, int n_in,
                              void* d_out, int out_size, void* d_ws, size_t ws_size,
                              hipStream_t stream) {
    const float* x     = (const float*)d_in[0];
    const float* c1_bw = (const float*)d_in[1];
    const float* c1_sw = (const float*)d_in[2];
    const float* c1_sc = (const float*)d_in[3];
    const float* c2_bw = (const float*)d_in[4];
    const float* c2_sw = (const float*)d_in[5];
    const float* c2_sc = (const float*)d_in[6];
    const float* c3_bw = (const float*)d_in[7];
    const float* c3_sw = (const float*)d_in[8];
    const float* c3_sc = (const float*)d_in[9];
    const float* lin_w = (const float*)d_in[10];
    const float* lin_b = (const float*)d_in[11];
    float* out = (float*)d_out;

    float* ws = (float*)d_ws;
    float* h1 = ws;                 // 256*8*16*16  = 524288 floats
    float* h2 = h1 + 524288;        // 256*16*8*8   = 262144
    float* h3 = h2 + 262144;        // 256*32*4*4   = 131072
    float* w1 = h3 + 131072;        // 27*8*8   = 1728
    float* w2 = w1 + 1728;          // 72*16*8  = 9216
    float* w3 = w2 + 9216;          // 144*32*8 = 36864
    // total 965312 floats = 3.9 MB

    prep_weights<<<24, 256, 0, stream>>>(
        c1_bw, c1_sw, c1_sc, c2_bw, c2_sw, c2_sc, c3_bw, c3_sw, c3_sc,
        w1, w2, w3);

    // L1: x[256,3,32,32] -> h1[256,8,16,16]
    //     CR=4 (VS=8), CPF=1 (FS=3, NA=384=NT), LDS 20.2KB -> 5 blk/CU.
    kan_conv<3, 8, 8, 32, 32, 4, 1, 384, 1, 1><<<2048, 384, 0, stream>>>(x, w1, h1);
    // L2: h1 -> h2[256,16,8,8]
    //     CR=4 (VS=4), CPF=2 (FS=4, NA=256=NT), LDS 29.2KB -> 5 blk/CU.
    kan_conv<8, 16, 16, 16, 16, 4, 2, 256, 1, 1><<<1024, 256, 0, stream>>>(h1, w2, h2);
    // L3: h2 -> h3[256,32,4,4]
    //     CR=8 (VS=1), CPF=2 (FS=8, NA=512=NT), OS=2, PAD=0: LDS 51.2KB -> 3 blk/CU.
    kan_conv<16, 32, 16, 8, 8, 8, 2, 512, 2, 0><<<512, 512, 0, stream>>>(h2, w3, h3);
    // Linear: h3[256,512] @ lin_w[100,512]^T + lin_b -> out[256,100]
    linear_kernel<<<100, 256, 0, stream>>>(h3, lin_w, lin_b, out);
}